// Round 13
// baseline (477.661 us; speedup 1.0000x reference)
//
#include <hip/hip_runtime.h>
#include <hip/hip_bf16.h>

// ---------------------------------------------------------------------------
// DynamicFeaturePyramid forward, MI355X.
// R13: split-K last-block-combines fusion. 3 dispatches: k_prep, k_qkv,
// k_attn_fused. Each (b,qg) has 4 key-split blocks; the last arriver (device
// -scope counter) combines partials and runs the out-proj/gate GEMMs for its
// 128 queries; the last combiner per b runs the x2/3/4 downsample. No grid
// drains between attention, out-proj, and final gating.
// Workspace: Q 0..4M, K 4M..8M, Vt 8M..12M, Op 12.6M..29.36M,
// Lp 29.36M..29.88M, WTb/bqkv/owb/g1wb/g2wb 29.88M..29.97M,
// cnt 29.97M (+2KB), SWb2 (96ch) 29.97M..36.26M.
// ---------------------------------------------------------------------------

typedef __attribute__((ext_vector_type(8))) short s16x8;    // 8 bf16 = 4 VGPRs
typedef __attribute__((ext_vector_type(4))) float f32x4;    // 16x16 C/D frag
typedef __attribute__((ext_vector_type(16))) float f32x16;  // 32x32 C/D frag

#define LOG2E 1.44269504088896340736f

__device__ __forceinline__ unsigned int f2bf(float f) {
    unsigned int u = __float_as_uint(f);
    u += 0x7fffu + ((u >> 16) & 1u);   // RNE (inputs finite)
    return u >> 16;
}
__device__ __forceinline__ unsigned int pk2bf(float a, float b) {
    union { __hip_bfloat162 h; unsigned int u; } cv;
    cv.h = __float22bfloat162_rn(make_float2(a, b));   // v_cvt_pk_bf16_f32
    return cv.u;
}
__device__ __forceinline__ float bf2f(unsigned short u) {
    return __uint_as_float((unsigned int)u << 16);
}
__device__ __forceinline__ float fexp2(float x) { return __builtin_amdgcn_exp2f(x); }
__device__ __forceinline__ float frcp(float x)  { return __builtin_amdgcn_rcpf(x); }

// ---------------------------------------------------------------------------
// K0: weight prep. WTb[oc][c] bf16 (q rows *log2e), bqkv fp32, owb/g1wb/g2wb
// bf16 straight casts.
// ---------------------------------------------------------------------------
__global__ __launch_bounds__(256) void k_prep(
    const float* __restrict__ qw, const float* __restrict__ qb,
    const float* __restrict__ kw, const float* __restrict__ kb,
    const float* __restrict__ vw, const float* __restrict__ vb,
    const float* __restrict__ ow, const float* __restrict__ g1w,
    const float* __restrict__ g2w,
    unsigned short* __restrict__ WTb, float* __restrict__ bqkv,
    unsigned short* __restrict__ owb, unsigned short* __restrict__ g1wb,
    unsigned short* __restrict__ g2wb) {
  int t = blockIdx.x * 256 + threadIdx.x;
  if (t < 192 * 128) {            // WTb[oc][c]
    int oc = t >> 7, c = t & 127;
    float v;
    if (oc < 64)       v = qw[oc * 128 + c] * LOG2E;
    else if (oc < 128) v = kw[(oc - 64) * 128 + c];
    else               v = vw[(oc - 128) * 128 + c];
    WTb[t] = (unsigned short)f2bf(v);
  }
  if (t < 192) {
    float v;
    if (t < 64)       v = qb[t] * LOG2E;
    else if (t < 128) v = kb[t - 64];
    else              v = vb[t - 128];
    bqkv[t] = v;
  }
  if (t < 128 * 64) owb[t]  = (unsigned short)f2bf(ow[t]);
  if (t < 32 * 128) g1wb[t] = (unsigned short)f2bf(g1w[t]);
  if (t < 128 * 32) g2wb[t] = (unsigned short)f2bf(g2w[t]);
}

// ---------------------------------------------------------------------------
// K1: upsample+concat -> gf bf16 [pos][c] (32-pos tile) -> MFMA QKV proj.
// Grid 1024, 4 blocks/CU. [R12, unchanged]
// ---------------------------------------------------------------------------
__global__ __launch_bounds__(256, 4) void k_qkv(
    const float* __restrict__ x1, const float* __restrict__ x2,
    const float* __restrict__ x3, const float* __restrict__ x4,
    const unsigned short* __restrict__ WTb, const float* __restrict__ bqkv,
    unsigned short* __restrict__ Qg, unsigned short* __restrict__ Kg,
    unsigned short* __restrict__ Vg) {
  __shared__ __align__(16) unsigned short gfb[32 * 136];    // [pos][c]
  unsigned int* gfbu = (unsigned int*)gfb;                  // pos*68 + cp

  const int blk = blockIdx.x;
  const int b = blk >> 7;
  const int i0 = (blk & 127) << 5;
  const int t = threadIdx.x;
  const int wv = t >> 6, lane = t & 63;
  const int r = lane & 15, qd = lane >> 4;
  f32x4 zf = {0.f, 0.f, 0.f, 0.f};

  {
    const int cp = t >> 2, q = t & 3;
    const int c0 = cp << 1;
    const int pbase = q << 3;                   // 8 positions each
    const int oy = i0 >> 6;
    const int ox0 = (i0 & 63) | (q << 3);

    if (cp < 16) {                              // x1 direct, 2 channels
      const float* s0 = x1 + (((b * 32 + c0) << 12) + (oy << 6) + ox0);
      const float* s1 = s0 + 4096;
      #pragma unroll
      for (int k4 = 0; k4 < 2; k4++) {
        float4 va = ((const float4*)s0)[k4];
        float4 vb = ((const float4*)s1)[k4];
        int p = pbase + k4 * 4;
        gfbu[(p + 0) * 68 + cp] = pk2bf(va.x, vb.x);
        gfbu[(p + 1) * 68 + cp] = pk2bf(va.y, vb.y);
        gfbu[(p + 2) * 68 + cp] = pk2bf(va.z, vb.z);
        gfbu[(p + 3) * 68 + cp] = pk2bf(va.w, vb.w);
      }
    } else {                                    // bilinear upsample, 2 ch
      const float* base; int S, cs;
      if (cp < 32)      { base = x2; S = 32; cs = c0 - 32; }
      else if (cp < 48) { base = x3; S = 16; cs = c0 - 64; }
      else              { base = x4; S = 8;  cs = c0 - 96; }
      const float* pl0 = base + (b * 32 + cs) * S * S;
      const float* pl1 = pl0 + S * S;
      float yf = (float)oy * (float)(S - 1) * (1.0f / 63.0f);
      int y0 = (int)yf; if (y0 > S - 1) y0 = S - 1;
      int y1 = y0 + 1;  if (y1 > S - 1) y1 = S - 1;
      float wy = yf - (float)y0;
      const float* r00 = pl0 + y0 * S; const float* r01 = pl0 + y1 * S;
      const float* r10 = pl1 + y0 * S; const float* r11 = pl1 + y1 * S;
      for (int k = 0; k < 8; k++) {
        int ox = ox0 + k;
        float xf = (float)ox * (float)(S - 1) * (1.0f / 63.0f);
        int xx0 = (int)xf; if (xx0 > S - 1) xx0 = S - 1;
        int xx1 = xx0 + 1; if (xx1 > S - 1) xx1 = S - 1;
        float wx = xf - (float)xx0;
        float a0 = r00[xx0] + wx * (r00[xx1] - r00[xx0]);
        float b0 = r01[xx0] + wx * (r01[xx1] - r01[xx0]);
        float v0 = a0 + wy * (b0 - a0);
        float a1 = r10[xx0] + wx * (r10[xx1] - r10[xx0]);
        float b1 = r11[xx0] + wx * (r11[xx1] - r11[xx0]);
        float v1 = a1 + wy * (b1 - a1);
        gfbu[(pbase + k) * 68 + cp] = pk2bf(v0, v1);
      }
    }
  }
  __syncthreads();

  const int ocb = wv * 48;
  s16x8 af[3][4];
  float4 bias[3];
  #pragma unroll
  for (int mti = 0; mti < 3; mti++) {
    #pragma unroll
    for (int ks = 0; ks < 4; ks++)
      af[mti][ks] = *(const s16x8*)&WTb[(ocb + mti * 16 + r) * 128 + ks * 32 + qd * 8];
    bias[mti] = *(const float4*)&bqkv[ocb + mti * 16 + qd * 4];
  }

  #pragma unroll
  for (int nt = 0; nt < 2; nt++) {
    s16x8 bfr[4];
    #pragma unroll
    for (int ks = 0; ks < 4; ks++)
      bfr[ks] = *(const s16x8*)&gfb[(nt * 16 + r) * 136 + ks * 32 + qd * 8];
    f32x4 acc[3] = {zf, zf, zf};
    #pragma unroll
    for (int ks = 0; ks < 4; ks++)
      #pragma unroll
      for (int mti = 0; mti < 3; mti++)
        acc[mti] = __builtin_amdgcn_mfma_f32_16x16x32_bf16(af[mti][ks], bfr[ks], acc[mti], 0, 0, 0);

    const int pos = i0 + nt * 16 + r;
    #pragma unroll
    for (int mti = 0; mti < 3; mti++) {
      const int gmt = wv * 3 + mti;
      float ax = acc[mti].x + bias[mti].x;
      float ay = acc[mti].y + bias[mti].y;
      float az = acc[mti].z + bias[mti].z;
      float aw = acc[mti].w + bias[mti].w;
      if (gmt < 4) {
        uint2 w; w.x = pk2bf(ax, ay); w.y = pk2bf(az, aw);
        *(uint2*)&Qg[(((b << 12) + pos) << 6) + gmt * 16 + qd * 4] = w;
      } else if (gmt < 8) {
        uint2 w; w.x = pk2bf(ax, ay); w.y = pk2bf(az, aw);
        *(uint2*)&Kg[(((b << 12) + pos) << 6) + (gmt - 4) * 16 + qd * 4] = w;
      } else {
        int ocv = (gmt - 8) * 16 + qd * 4;
        Vg[((b * 64 + ocv + 0) << 12) + pos] = (unsigned short)f2bf(ax);
        Vg[((b * 64 + ocv + 1) << 12) + pos] = (unsigned short)f2bf(ay);
        Vg[((b * 64 + ocv + 2) << 12) + pos] = (unsigned short)f2bf(az);
        Vg[((b * 64 + ocv + 3) << 12) + pos] = (unsigned short)f2bf(aw);
      }
    }
  }
}

// ---------------------------------------------------------------------------
// K2: fused attention + split-K combine + out-proj/gates + final downsample.
// Attention body = R12 (32x32 MFMA, lane^32 P exchange, dbuf staging).
// After epilogue: fence + atomicAdd(cnt1[b*32+qg]); last of 4 parts combines
// Op -> runs GEMM1/2/3 (+x1 gate) over its 128 queries (4 x 32-pos tiles),
// then fence + atomicAdd(cnt2[b]); last of 32 combiners per b runs the
// x2/3/4 gated downsample for batch b.
// ---------------------------------------------------------------------------
__global__ __launch_bounds__(256, 4) void k_attn(
    const unsigned short* __restrict__ Qg, const unsigned short* __restrict__ Kg,
    const unsigned short* __restrict__ Vg, unsigned short* __restrict__ Op,
    float* __restrict__ Lp,
    const unsigned short* __restrict__ owb, const float* __restrict__ obias,
    const unsigned short* __restrict__ g1wb, const float* __restrict__ g1b,
    const unsigned short* __restrict__ g2wb, const float* __restrict__ g2b,
    const float* __restrict__ x1, const float* __restrict__ x2,
    const float* __restrict__ x3, const float* __restrict__ x4,
    float* __restrict__ out, unsigned short* __restrict__ SWb2,
    unsigned int* __restrict__ cnt1, unsigned int* __restrict__ cnt2) {
  __shared__ __align__(16) unsigned short Kl[2][64 * 72];   // [key][dim]
  __shared__ __align__(16) unsigned short Vl[2][64 * 72];   // [dim][key]
  __shared__ unsigned int whoS;

  const int b = blockIdx.x >> 7;
  const int part = (blockIdx.x >> 5) & 3;
  const int qg = blockIdx.x & 31;
  const int i0 = qg << 7;
  const int t = threadIdx.x;
  const int wv = t >> 6, lane = t & 63;
  const int q = lane & 31, hi = lane >> 5;
  const int qbase = i0 + wv * 32;

  // ---------------- attention (R12 body) ----------------
  {
    s16x8 qf[4];
    #pragma unroll
    for (int kc = 0; kc < 4; kc++)
      qf[kc] = *(const s16x8*)&Qg[(((b << 12) + qbase + q) << 6) + kc * 16 + hi * 8];

    f32x16 acc[2];
    #pragma unroll
    for (int m = 0; m < 2; m++)
      #pragma unroll
      for (int e = 0; e < 16; e++) acc[m][e] = 0.f;
    float ls = 0.f;

    const int srow = t >> 3, sseg = t & 7;
    const unsigned short* kt0 = &Kg[(((b << 12) + (part << 10) + srow) << 6) + sseg * 8];
    const unsigned short* vt0 = &Vg[((b * 64 + srow) << 12) + (part << 10) + sseg * 8];
    uint4 pk0 = *(const uint4*)(kt0);
    uint4 pk1 = *(const uint4*)(kt0 + (32 << 6));
    uint4 pv0 = *(const uint4*)(vt0);
    uint4 pv1 = *(const uint4*)(vt0 + (32 << 12));

    for (int it = 0; it < 16; it++) {
      unsigned short* Kb = Kl[it & 1];
      unsigned short* Vb = Vl[it & 1];
      *(uint4*)&Kb[srow * 72 + sseg * 8] = pk0;
      *(uint4*)&Kb[(srow + 32) * 72 + sseg * 8] = pk1;
      *(uint4*)&Vb[srow * 72 + sseg * 8] = pv0;
      *(uint4*)&Vb[(srow + 32) * 72 + sseg * 8] = pv1;
      __syncthreads();
      if (it < 15) {
        int j0 = (it + 1) << 6;
        pk0 = *(const uint4*)(kt0 + (j0 << 6));
        pk1 = *(const uint4*)(kt0 + ((j0 + 32) << 6));
        pv0 = *(const uint4*)(vt0 + j0);
        pv1 = *(const uint4*)(vt0 + (32 << 12) + j0);
      }

      unsigned int pu[2][8];
      #pragma unroll
      for (int kt = 0; kt < 2; kt++) {
        f32x16 st;
        #pragma unroll
        for (int e = 0; e < 16; e++) st[e] = 0.f;
        #pragma unroll
        for (int kc = 0; kc < 4; kc++) {
          s16x8 kf = *(const s16x8*)&Kb[(kt * 32 + q) * 72 + kc * 16 + hi * 8];
          st = __builtin_amdgcn_mfma_f32_32x32x16_bf16(kf, qf[kc], st, 0, 0, 0);
        }
        float lsum = 0.f;
        #pragma unroll
        for (int i2 = 0; i2 < 8; i2++) {
          float p0 = fexp2(st[2 * i2]);
          float p1 = fexp2(st[2 * i2 + 1]);
          lsum += p0 + p1;
          pu[kt][i2] = pk2bf(p0, p1);
        }
        ls += lsum;
      }

      #pragma unroll
      for (int kt = 0; kt < 2; kt++) {
        #pragma unroll
        for (int c16 = 0; c16 < 2; c16++) {
          const int c16g = kt * 2 + c16;
          unsigned int a0 = pu[kt][c16 * 4 + 0], a1 = pu[kt][c16 * 4 + 1];
          unsigned int a2 = pu[kt][c16 * 4 + 2], a3 = pu[kt][c16 * 4 + 3];
          unsigned int k0 = hi ? a2 : a0, k1 = hi ? a3 : a1;
          unsigned int s0 = hi ? a0 : a2, s1 = hi ? a1 : a3;
          unsigned int r0 = __shfl_xor(s0, 32);
          unsigned int r1 = __shfl_xor(s1, 32);
          union { s16x8 v; unsigned int u[4]; } pb;
          pb.u[0] = hi ? r0 : k0;
          pb.u[1] = hi ? r1 : k1;
          pb.u[2] = hi ? k0 : r0;
          pb.u[3] = hi ? k1 : r1;
          #pragma unroll
          for (int mtv = 0; mtv < 2; mtv++) {
            s16x8 vf = *(const s16x8*)&Vl[it & 1][(mtv * 32 + q) * 72 + c16g * 16 + hi * 8];
            acc[mtv] = __builtin_amdgcn_mfma_f32_32x32x16_bf16(vf, pb.v, acc[mtv], 0, 0, 0);
          }
        }
      }
    }

    ls += __shfl_xor(ls, 32);
    float inv = frcp(ls);
    const int qrow = qbase + q;
    unsigned short* orow = &Op[(((part * 8 + b) << 12) + qrow) << 6];
    #pragma unroll
    for (int mtv = 0; mtv < 2; mtv++) {
      #pragma unroll
      for (int i2 = 0; i2 < 8; i2++) {
        int dbase = ((2 * i2) & 3) + 8 * ((2 * i2) >> 2) + 4 * hi + mtv * 32;
        *(unsigned int*)&orow[dbase] =
            pk2bf(acc[mtv][2 * i2] * inv, acc[mtv][2 * i2 + 1] * inv);
      }
    }
    if (hi == 0) Lp[((part * 8 + b) << 12) + qrow] = ls;
  }

  // ---------------- split-K completion counter ----------------
  __threadfence();                              // release Op/Lp writes
  __syncthreads();
  if (t == 0) whoS = atomicAdd(&cnt1[(b << 5) + qg], 1u);
  __syncthreads();
  if (whoS != 3) return;                        // not the last part
  __threadfence();                              // acquire other parts' writes

  // ---------------- combine + out-proj + gates (k_out body) ----------------
  unsigned short* Ot   = &Kl[0][0];             // 32 x 72   (2304)
  unsigned short* gf2t = Ot + 2304;             // 32 x 136  (4352)
  unsigned short* ht   = gf2t + 4352;           // 32 x 40   (1280) -> 7936 tot
  const int r = lane & 15, qd = lane >> 4;
  f32x4 zf = {0.f, 0.f, 0.f, 0.f};

  for (int sub = 0; sub < 4; sub++) {
    const int i0c = i0 + sub * 32;
    __syncthreads();                            // LDS reuse safe

    {
      const int pos = t >> 3, seg = t & 7;
      const int i = i0c + pos;
      float lp4[4], lsum = 0.f;
      #pragma unroll
      for (int p = 0; p < 4; p++) { lp4[p] = Lp[((p * 8 + b) << 12) + i]; lsum += lp4[p]; }
      float o[8];
      #pragma unroll
      for (int k = 0; k < 8; k++) o[k] = 0.f;
      float invs = frcp(lsum);
      #pragma unroll
      for (int p = 0; p < 4; p++) {
        float w = lp4[p] * invs;
        uint4 u = *(const uint4*)&Op[((((p * 8 + b) << 12) + i) << 6) + seg * 8];
        o[0] += w * __uint_as_float(u.x << 16);
        o[1] += w * __uint_as_float(u.x & 0xFFFF0000u);
        o[2] += w * __uint_as_float(u.y << 16);
        o[3] += w * __uint_as_float(u.y & 0xFFFF0000u);
        o[4] += w * __uint_as_float(u.z << 16);
        o[5] += w * __uint_as_float(u.z & 0xFFFF0000u);
        o[6] += w * __uint_as_float(u.w << 16);
        o[7] += w * __uint_as_float(u.w & 0xFFFF0000u);
      }
      unsigned int* dst = (unsigned int*)&Ot[pos * 72 + seg * 8];
      #pragma unroll
      for (int k = 0; k < 4; k++) dst[k] = pk2bf(o[2 * k], o[2 * k + 1]);
    }
    __syncthreads();

    // GEMM1: gf2[oc=128][pos=32] = owb(128x64) * Ot^T; wave -> 32 oc
    {
      const int ocb = wv * 32;
      s16x8 af[2][2];
      #pragma unroll
      for (int mt = 0; mt < 2; mt++)
        #pragma unroll
        for (int ks = 0; ks < 2; ks++)
          af[mt][ks] = *(const s16x8*)&owb[(ocb + mt * 16 + r) * 64 + ks * 32 + qd * 8];
      float4 bias[2];
      #pragma unroll
      for (int mt = 0; mt < 2; mt++)
        bias[mt] = *(const float4*)&obias[ocb + mt * 16 + qd * 4];
      #pragma unroll
      for (int nt = 0; nt < 2; nt++) {
        s16x8 bfr[2];
        #pragma unroll
        for (int ks = 0; ks < 2; ks++)
          bfr[ks] = *(const s16x8*)&Ot[(nt * 16 + r) * 72 + ks * 32 + qd * 8];
        f32x4 acc2[2] = {zf, zf};
        #pragma unroll
        for (int ks = 0; ks < 2; ks++)
          #pragma unroll
          for (int mt = 0; mt < 2; mt++)
            acc2[mt] = __builtin_amdgcn_mfma_f32_16x16x32_bf16(af[mt][ks], bfr[ks], acc2[mt], 0, 0, 0);
        #pragma unroll
        for (int mt = 0; mt < 2; mt++) {
          uint2 w;
          w.x = pk2bf(acc2[mt].x + bias[mt].x, acc2[mt].y + bias[mt].y);
          w.y = pk2bf(acc2[mt].z + bias[mt].z, acc2[mt].w + bias[mt].w);
          *(uint2*)&gf2t[(nt * 16 + r) * 136 + ocb + mt * 16 + qd * 4] = w;
        }
      }
    }
    __syncthreads();

    // GEMM2: h[oc2=32][pos=32] = g1wb(32x128)*gf2t^T; wave -> (mt, pos-tile)
    {
      const int mt = wv & 1, pt = wv >> 1;
      s16x8 af[4];
      #pragma unroll
      for (int ks = 0; ks < 4; ks++)
        af[ks] = *(const s16x8*)&g1wb[(mt * 16 + r) * 128 + ks * 32 + qd * 8];
      float4 bias = *(const float4*)&g1b[mt * 16 + qd * 4];
      s16x8 bfr[4];
      #pragma unroll
      for (int ks = 0; ks < 4; ks++)
        bfr[ks] = *(const s16x8*)&gf2t[(pt * 16 + r) * 136 + ks * 32 + qd * 8];
      f32x4 acc2 = zf;
      #pragma unroll
      for (int ks = 0; ks < 4; ks++)
        acc2 = __builtin_amdgcn_mfma_f32_16x16x32_bf16(af[ks], bfr[ks], acc2, 0, 0, 0);
      uint2 w;
      w.x = pk2bf(fmaxf(acc2.x + bias.x, 0.f), fmaxf(acc2.y + bias.y, 0.f));
      w.y = pk2bf(fmaxf(acc2.z + bias.z, 0.f), fmaxf(acc2.w + bias.w, 0.f));
      *(uint2*)&ht[(pt * 16 + r) * 40 + mt * 16 + qd * 4] = w;
    }
    __syncthreads();

    // GEMM3 (swapped): sw[pos][oc3]; wave0 fuses x1 gate; others -> SWb2
    {
      const int nb = wv * 32;
      s16x8 bfg[2];
      float bias[2];
      #pragma unroll
      for (int ntl = 0; ntl < 2; ntl++) {
        bfg[ntl] = *(const s16x8*)&g2wb[(nb + ntl * 16 + r) * 32 + qd * 8];
        bias[ntl] = g2b[nb + ntl * 16 + r];
      }
      #pragma unroll
      for (int mt = 0; mt < 2; mt++) {
        s16x8 af = *(const s16x8*)&ht[(mt * 16 + r) * 40 + qd * 8];
        #pragma unroll
        for (int ntl = 0; ntl < 2; ntl++) {
          f32x4 acc2 = __builtin_amdgcn_mfma_f32_16x16x32_bf16(af, bfg[ntl], zf, 0, 0, 0);
          const int oc3 = nb + ntl * 16 + r;
          float s0 = frcp(1.0f + fexp2(-LOG2E * (acc2.x + bias[ntl])));
          float s1 = frcp(1.0f + fexp2(-LOG2E * (acc2.y + bias[ntl])));
          float s2 = frcp(1.0f + fexp2(-LOG2E * (acc2.z + bias[ntl])));
          float s3 = frcp(1.0f + fexp2(-LOG2E * (acc2.w + bias[ntl])));
          if (nb == 0) {                        // x1 gate (oc3 < 32)
            const int off = ((b * 32 + oc3) << 12) + i0c + mt * 16 + qd * 4;
            float4 xv = *(const float4*)&x1[off];
            float4 o4;
            o4.x = xv.x * (1.f + s0); o4.y = xv.y * (1.f + s1);
            o4.z = xv.z * (1.f + s2); o4.w = xv.w * (1.f + s3);
            *(float4*)&out[off] = o4;
          } else {                              // SWb2: channels 32..127
            uint2 w; w.x = pk2bf(s0, s1); w.y = pk2bf(s2, s3);
            *(uint2*)&SWb2[((b * 96 + (oc3 - 32)) << 12) + i0c + mt * 16 + qd * 4] = w;
          }
        }
      }
    }
  }

  // ---------------- per-batch completion -> downsample gates ----------------
  __threadfence();
  __syncthreads();
  if (t == 0) whoS = atomicAdd(&cnt2[b], 1u);
  __syncthreads();
  if (whoS != 31) return;
  __threadfence();

  {
    const int N1 = 1048576;
    for (int idx = t; idx < 43008; idx += 256) {
      if (idx < 32768) {                        // x2: 32 ch, 32x32
        int c = idx >> 10, oy = (idx >> 5) & 31, ox = idx & 31;
        const unsigned short* p = SWb2 + ((b * 96 + c) << 12);
        float yf = (float)oy * 63.0f / 31.0f;
        int y0 = (int)yf; if (y0 > 63) y0 = 63;
        int y1 = y0 + 1;  if (y1 > 63) y1 = 63;
        float wy = yf - (float)y0;
        float xf = (float)ox * 63.0f / 31.0f;
        int x0 = (int)xf; if (x0 > 63) x0 = 63;
        int xx1 = x0 + 1; if (xx1 > 63) xx1 = 63;
        float wx = xf - (float)x0;
        float v00 = bf2f(p[y0 * 64 + x0]), v01 = bf2f(p[y0 * 64 + xx1]);
        float v10 = bf2f(p[y1 * 64 + x0]), v11 = bf2f(p[y1 * 64 + xx1]);
        float top = v00 + wx * (v01 - v00);
        float bot = v10 + wx * (v11 - v10);
        float w = top + wy * (bot - top);
        int gi = b * 32768 + idx;
        out[N1 + gi] = x2[gi] * (1.f + w);
      } else if (idx < 40960) {                 // x3: 32 ch, 16x16
        int j = idx - 32768;
        int c = j >> 8, oy = (j >> 4) & 15, ox = j & 15;
        const unsigned short* p = SWb2 + ((b * 96 + 32 + c) << 12);
        float yf = (float)oy * 63.0f / 15.0f;
        int y0 = (int)yf; if (y0 > 63) y0 = 63;
        int y1 = y0 + 1;  if (y1 > 63) y1 = 63;
        float wy = yf - (float)y0;
        float xf = (float)ox * 63.0f / 15.0f;
        int x0 = (int)xf; if (x0 > 63) x0 = 63;
        int xx1 = x0 + 1; if (xx1 > 63) xx1 = 63;
        float wx = xf - (float)x0;
        float v00 = bf2f(p[y0 * 64 + x0]), v01 = bf2f(p[y0 * 64 + xx1]);
        float v10 = bf2f(p[y1 * 64 + x0]), v11 = bf2f(p[y1 * 64 + xx1]);
        float top = v00 + wx * (v01 - v00);
        float bot = v10 + wx * (v11 - v10);
        float w = top + wy * (bot - top);
        int gi = b * 8192 + j;
        out[N1 + 262144 + gi] = x3[gi] * (1.f + w);
      } else {                                  // x4: 32 ch, 8x8
        int j = idx - 40960;
        int c = j >> 6, oy = (j >> 3) & 7, ox = j & 7;
        const unsigned short* p = SWb2 + ((b * 96 + 64 + c) << 12);
        float yf = (float)oy * 63.0f / 7.0f;
        int y0 = (int)yf; if (y0 > 63) y0 = 63;
        int y1 = y0 + 1;  if (y1 > 63) y1 = 63;
        float wy = yf - (float)y0;
        float xf = (float)ox * 63.0f / 7.0f;
        int x0 = (int)xf; if (x0 > 63) x0 = 63;
        int xx1 = x0 + 1; if (xx1 > 63) xx1 = 63;
        float wx = xf - (float)x0;
        float v00 = bf2f(p[y0 * 64 + x0]), v01 = bf2f(p[y0 * 64 + xx1]);
        float v10 = bf2f(p[y1 * 64 + x0]), v11 = bf2f(p[y1 * 64 + xx1]);
        float top = v00 + wx * (v01 - v00);
        float bot = v10 + wx * (v11 - v10);
        float w = top + wy * (bot - top);
        int gi = b * 2048 + j;
        out[N1 + 262144 + 65536 + gi] = x4[gi] * (1.f + w);
      }
    }
  }
}

// ---------------------------------------------------------------------------
extern "C" void kernel_launch(void* const* d_in, const int* in_sizes, int n_in,
                              void* d_out, int out_size, void* d_ws, size_t ws_size,
                              hipStream_t stream) {
  const float* x1  = (const float*)d_in[0];
  const float* x2  = (const float*)d_in[1];
  const float* x3  = (const float*)d_in[2];
  const float* x4  = (const float*)d_in[3];
  const float* qw  = (const float*)d_in[4];
  const float* qb  = (const float*)d_in[5];
  const float* kw  = (const float*)d_in[6];
  const float* kb  = (const float*)d_in[7];
  const float* vw  = (const float*)d_in[8];
  const float* vb  = (const float*)d_in[9];
  const float* ow  = (const float*)d_in[10];
  const float* ob  = (const float*)d_in[11];
  const float* g1w = (const float*)d_in[12];
  const float* g1b = (const float*)d_in[13];
  const float* g2w = (const float*)d_in[14];
  const float* g2b = (const float*)d_in[15];
  float* out = (float*)d_out;

  char* ws = (char*)d_ws;
  unsigned short* Qg  = (unsigned short*)(ws + 0);
  unsigned short* Kg  = (unsigned short*)(ws + 4194304);
  unsigned short* Vg  = (unsigned short*)(ws + 8388608);
  unsigned short* Op  = (unsigned short*)(ws + 12582912);
  float* Lp   = (float*)(ws + 29360128);
  unsigned short* WTb = (unsigned short*)(ws + 29884416);
  float* bqkv = (float*)(ws + 29933568);
  unsigned short* owb  = (unsigned short*)(ws + 29934592);
  unsigned short* g1wb = (unsigned short*)(ws + 29950976);
  unsigned short* g2wb = (unsigned short*)(ws + 29959168);
  unsigned int* cnt1 = (unsigned int*)(ws + 29967360);   // 256 u32
  unsigned int* cnt2 = (unsigned int*)(ws + 29968384);   // 8 u32
  unsigned short* SWb2 = (unsigned short*)(ws + 29969408); // 96ch x 4096 x 8b

  hipMemsetAsync(ws + 29967360, 0, 2048, stream);
  k_prep<<<96, 256, 0, stream>>>(qw, qb, kw, kb, vw, vb, ow, g1w, g2w,
                                 WTb, bqkv, owb, g1wb, g2wb);
  k_qkv<<<1024, 256, 0, stream>>>(x1, x2, x3, x4, WTb, bqkv, Qg, Kg, Vg);
  k_attn<<<1024, 256, 0, stream>>>(Qg, Kg, Vg, Op, Lp,
                                   owb, ob, g1wb, g1b, g2wb, g2b,
                                   x1, x2, x3, x4, out, SWb2, cnt1, cnt2);
}

// Round 14
// 162.436 us; speedup vs baseline: 2.9406x; 2.9406x over previous
//
#include <hip/hip_runtime.h>
#include <hip/hip_bf16.h>

// ---------------------------------------------------------------------------
// DynamicFeaturePyramid forward, MI355X.
// R14 = R12 (best: 173.8us) + k_qkv bilinear sources staged through LDS
// (replaces 32 lane-divergent scalar global gathers/thread with coalesced
// float4 block loads). R13's per-block __threadfence split-K fusion was a
// 7x regression (device-scope fence = L2 writeback storm) -- reverted.
// Workspace: Q 0..4M, K 4M..8M, Vt 8M..12M, SWb aliases 0..8M (phase 3+),
// Op 12.6M..29.4M, Lp 29.4M..29.9M, WTb/bqkv/owb/g1wb/g2wb 29.88M..29.97M.
// ---------------------------------------------------------------------------

typedef __attribute__((ext_vector_type(8))) short s16x8;    // 8 bf16 = 4 VGPRs
typedef __attribute__((ext_vector_type(4))) float f32x4;    // 16x16 C/D frag
typedef __attribute__((ext_vector_type(16))) float f32x16;  // 32x32 C/D frag

#define LOG2E 1.44269504088896340736f

__device__ __forceinline__ unsigned int f2bf(float f) {
    unsigned int u = __float_as_uint(f);
    u += 0x7fffu + ((u >> 16) & 1u);   // RNE (inputs finite)
    return u >> 16;
}
__device__ __forceinline__ unsigned int pk2bf(float a, float b) {
    union { __hip_bfloat162 h; unsigned int u; } cv;
    cv.h = __float22bfloat162_rn(make_float2(a, b));   // v_cvt_pk_bf16_f32
    return cv.u;
}
__device__ __forceinline__ float bf2f(unsigned short u) {
    return __uint_as_float((unsigned int)u << 16);
}
__device__ __forceinline__ float fexp2(float x) { return __builtin_amdgcn_exp2f(x); }
__device__ __forceinline__ float frcp(float x)  { return __builtin_amdgcn_rcpf(x); }

// ---------------------------------------------------------------------------
// K0: weight prep. WTb[oc][c] bf16 (q rows *log2e), bqkv fp32, owb/g1wb/g2wb
// bf16 straight casts.
// ---------------------------------------------------------------------------
__global__ __launch_bounds__(256) void k_prep(
    const float* __restrict__ qw, const float* __restrict__ qb,
    const float* __restrict__ kw, const float* __restrict__ kb,
    const float* __restrict__ vw, const float* __restrict__ vb,
    const float* __restrict__ ow, const float* __restrict__ g1w,
    const float* __restrict__ g2w,
    unsigned short* __restrict__ WTb, float* __restrict__ bqkv,
    unsigned short* __restrict__ owb, unsigned short* __restrict__ g1wb,
    unsigned short* __restrict__ g2wb) {
  int t = blockIdx.x * 256 + threadIdx.x;
  if (t < 192 * 128) {            // WTb[oc][c]
    int oc = t >> 7, c = t & 127;
    float v;
    if (oc < 64)       v = qw[oc * 128 + c] * LOG2E;
    else if (oc < 128) v = kw[(oc - 64) * 128 + c];
    else               v = vw[(oc - 128) * 128 + c];
    WTb[t] = (unsigned short)f2bf(v);
  }
  if (t < 192) {
    float v;
    if (t < 64)       v = qb[t] * LOG2E;
    else if (t < 128) v = kb[t - 64];
    else              v = vb[t - 128];
    bqkv[t] = v;
  }
  if (t < 128 * 64) owb[t]  = (unsigned short)f2bf(ow[t]);
  if (t < 32 * 128) g1wb[t] = (unsigned short)f2bf(g1w[t]);
  if (t < 128 * 32) g2wb[t] = (unsigned short)f2bf(g2w[t]);
}

// ---------------------------------------------------------------------------
// K1: upsample+concat -> gf bf16 [pos][c] (32-pos tile) -> MFMA QKV proj.
// Grid 1024, 4 blocks/CU. R14: x2/x3/x4 source rows (y0,y1 per source, fixed
// per block) staged into padded LDS via coalesced float4 loads; bilinear
// arithmetic (identical formulas) then reads LDS instead of global gathers.
// ---------------------------------------------------------------------------
__global__ __launch_bounds__(256, 4) void k_qkv(
    const float* __restrict__ x1, const float* __restrict__ x2,
    const float* __restrict__ x3, const float* __restrict__ x4,
    const unsigned short* __restrict__ WTb, const float* __restrict__ bqkv,
    unsigned short* __restrict__ Qg, unsigned short* __restrict__ Kg,
    unsigned short* __restrict__ Vg) {
  __shared__ __align__(16) unsigned short gfb[32 * 136];    // [pos][c] 8704 B
  __shared__ float srcb[3680];                              // 14720 B padded
  unsigned int* gfbu = (unsigned int*)gfb;                  // pos*68 + cp

  const int blk = blockIdx.x;
  const int b = blk >> 7;
  const int i0 = (blk & 127) << 5;
  const int t = threadIdx.x;
  const int wv = t >> 6, lane = t & 63;
  const int r = lane & 15, qd = lane >> 4;
  const int oy = i0 >> 6;
  f32x4 zf = {0.f, 0.f, 0.f, 0.f};

  // ---- stage source rows for x2/x3/x4 into LDS (coalesced float4) ----
  {
    // x2: 32 ch x 2 rows x 32 fl, channel stride 65 (pad 1)
    {
      float yf = (float)oy * 31.0f * (1.0f / 63.0f);
      int y0 = (int)yf; if (y0 > 31) y0 = 31;
      int y1 = y0 + 1;  if (y1 > 31) y1 = 31;
      #pragma unroll
      for (int f4 = 0; f4 < 2; f4++) {
        int id = t + f4 * 256;                  // 0..511
        int ch = id >> 4, rem = id & 15;
        int row01 = rem >> 3, xs = (rem & 7) << 2;
        int srow = row01 ? y1 : y0;
        float4 v = *(const float4*)&x2[(((b * 32 + ch) << 10)) + (srow << 5) + xs];
        float* d = &srcb[ch * 65 + row01 * 32 + xs];
        d[0] = v.x; d[1] = v.y; d[2] = v.z; d[3] = v.w;
      }
    }
    // x3: 32 ch x 2 rows x 16 fl, base 2080, channel stride 33
    {
      float yf = (float)oy * 15.0f * (1.0f / 63.0f);
      int y0 = (int)yf; if (y0 > 15) y0 = 15;
      int y1 = y0 + 1;  if (y1 > 15) y1 = 15;
      int ch = t >> 3, rem = t & 7;
      int row01 = rem >> 2, xs = (rem & 3) << 2;
      int srow = row01 ? y1 : y0;
      float4 v = *(const float4*)&x3[(((b * 32 + ch) << 8)) + (srow << 4) + xs];
      float* d = &srcb[2080 + ch * 33 + row01 * 16 + xs];
      d[0] = v.x; d[1] = v.y; d[2] = v.z; d[3] = v.w;
    }
    // x4: 32 ch x 2 rows x 8 fl, base 3136, channel stride 17
    if (t < 128) {
      float yf = (float)oy * 7.0f * (1.0f / 63.0f);
      int y0 = (int)yf; if (y0 > 7) y0 = 7;
      int y1 = y0 + 1;  if (y1 > 7) y1 = 7;
      int ch = t >> 2, rem = t & 3;
      int row01 = rem >> 1, xs = (rem & 1) << 2;
      int srow = row01 ? y1 : y0;
      float4 v = *(const float4*)&x4[(((b * 32 + ch) << 6)) + (srow << 3) + xs];
      float* d = &srcb[3136 + ch * 17 + row01 * 8 + xs];
      d[0] = v.x; d[1] = v.y; d[2] = v.z; d[3] = v.w;
    }
    // x1 direct path (cp<16): 2 channels -> gfb (unchanged)
    const int cp = t >> 2, q = t & 3;
    if (cp < 16) {
      const int c0 = cp << 1;
      const int pbase = q << 3;
      const int ox0 = (i0 & 63) | (q << 3);
      const float* s0 = x1 + (((b * 32 + c0) << 12) + (oy << 6) + ox0);
      const float* s1 = s0 + 4096;
      #pragma unroll
      for (int k4 = 0; k4 < 2; k4++) {
        float4 va = ((const float4*)s0)[k4];
        float4 vb = ((const float4*)s1)[k4];
        int p = pbase + k4 * 4;
        gfbu[(p + 0) * 68 + cp] = pk2bf(va.x, vb.x);
        gfbu[(p + 1) * 68 + cp] = pk2bf(va.y, vb.y);
        gfbu[(p + 2) * 68 + cp] = pk2bf(va.z, vb.z);
        gfbu[(p + 3) * 68 + cp] = pk2bf(va.w, vb.w);
      }
    }
  }
  __syncthreads();

  // ---- bilinear upsample from LDS (identical arithmetic) ----
  {
    const int cp = t >> 2, q = t & 3;
    if (cp >= 16) {
      const int c0 = cp << 1;
      const int pbase = q << 3;
      const int ox0 = (i0 & 63) | (q << 3);
      int S, baseo, choff;
      if (cp < 32)      { S = 32; baseo = 0;    choff = 32; }
      else if (cp < 48) { S = 16; baseo = 2080; choff = 64; }
      else              { S = 8;  baseo = 3136; choff = 96; }
      const int cstride = 2 * S + 1;
      const float* A = &srcb[baseo + (c0 - choff) * cstride];   // ch c0
      const float* B = A + cstride;                              // ch c0+1
      float yf = (float)oy * (float)(S - 1) * (1.0f / 63.0f);
      int y0i = (int)yf; if (y0i > S - 1) y0i = S - 1;
      float wy = yf - (float)y0i;
      for (int k = 0; k < 8; k++) {
        int ox = ox0 + k;
        float xf = (float)ox * (float)(S - 1) * (1.0f / 63.0f);
        int xx0 = (int)xf; if (xx0 > S - 1) xx0 = S - 1;
        int xx1 = xx0 + 1; if (xx1 > S - 1) xx1 = S - 1;
        float wx = xf - (float)xx0;
        float a0 = A[xx0] + wx * (A[xx1] - A[xx0]);             // ch c0, y0
        float b0 = A[S + xx0] + wx * (A[S + xx1] - A[S + xx0]); // ch c0, y1
        float v0 = a0 + wy * (b0 - a0);
        float a1 = B[xx0] + wx * (B[xx1] - B[xx0]);             // ch c0+1, y0
        float b1 = B[S + xx0] + wx * (B[S + xx1] - B[S + xx0]); // ch c0+1, y1
        float v1 = a1 + wy * (b1 - a1);
        gfbu[(pbase + k) * 68 + cp] = pk2bf(v0, v1);
      }
    }
  }
  __syncthreads();

  const int ocb = wv * 48;
  s16x8 af[3][4];
  float4 bias[3];
  #pragma unroll
  for (int mti = 0; mti < 3; mti++) {
    #pragma unroll
    for (int ks = 0; ks < 4; ks++)
      af[mti][ks] = *(const s16x8*)&WTb[(ocb + mti * 16 + r) * 128 + ks * 32 + qd * 8];
    bias[mti] = *(const float4*)&bqkv[ocb + mti * 16 + qd * 4];
  }

  #pragma unroll
  for (int nt = 0; nt < 2; nt++) {
    s16x8 bfr[4];
    #pragma unroll
    for (int ks = 0; ks < 4; ks++)
      bfr[ks] = *(const s16x8*)&gfb[(nt * 16 + r) * 136 + ks * 32 + qd * 8];
    f32x4 acc[3] = {zf, zf, zf};
    #pragma unroll
    for (int ks = 0; ks < 4; ks++)
      #pragma unroll
      for (int mti = 0; mti < 3; mti++)
        acc[mti] = __builtin_amdgcn_mfma_f32_16x16x32_bf16(af[mti][ks], bfr[ks], acc[mti], 0, 0, 0);

    const int pos = i0 + nt * 16 + r;
    #pragma unroll
    for (int mti = 0; mti < 3; mti++) {
      const int gmt = wv * 3 + mti;
      float ax = acc[mti].x + bias[mti].x;
      float ay = acc[mti].y + bias[mti].y;
      float az = acc[mti].z + bias[mti].z;
      float aw = acc[mti].w + bias[mti].w;
      if (gmt < 4) {
        uint2 w; w.x = pk2bf(ax, ay); w.y = pk2bf(az, aw);
        *(uint2*)&Qg[(((b << 12) + pos) << 6) + gmt * 16 + qd * 4] = w;
      } else if (gmt < 8) {
        uint2 w; w.x = pk2bf(ax, ay); w.y = pk2bf(az, aw);
        *(uint2*)&Kg[(((b << 12) + pos) << 6) + (gmt - 4) * 16 + qd * 4] = w;
      } else {
        int ocv = (gmt - 8) * 16 + qd * 4;
        Vg[((b * 64 + ocv + 0) << 12) + pos] = (unsigned short)f2bf(ax);
        Vg[((b * 64 + ocv + 1) << 12) + pos] = (unsigned short)f2bf(ay);
        Vg[((b * 64 + ocv + 2) << 12) + pos] = (unsigned short)f2bf(az);
        Vg[((b * 64 + ocv + 3) << 12) + pos] = (unsigned short)f2bf(aw);
      }
    }
  }
}

// ---------------------------------------------------------------------------
// K2: flash attention, 32x32x16 MFMA, P via lane^32 register exchange.
// Double-buffered K/V staging, single barrier per iteration. [R12, proven]
// ---------------------------------------------------------------------------
__global__ __launch_bounds__(256, 4) void k_attn(
    const unsigned short* __restrict__ Qg, const unsigned short* __restrict__ Kg,
    const unsigned short* __restrict__ Vg, unsigned short* __restrict__ Op,
    float* __restrict__ Lp) {
  __shared__ __align__(16) unsigned short Kl[2][64 * 72];   // [key][dim]
  __shared__ __align__(16) unsigned short Vl[2][64 * 72];   // [dim][key]

  const int b = blockIdx.x >> 7;
  const int part = (blockIdx.x >> 5) & 3;
  const int qg = blockIdx.x & 31;
  const int i0 = qg << 7;
  const int t = threadIdx.x;
  const int wv = t >> 6, lane = t & 63;
  const int q = lane & 31, hi = lane >> 5;
  const int qbase = i0 + wv * 32;

  s16x8 qf[4];
  #pragma unroll
  for (int kc = 0; kc < 4; kc++)
    qf[kc] = *(const s16x8*)&Qg[(((b << 12) + qbase + q) << 6) + kc * 16 + hi * 8];

  f32x16 acc[2];
  #pragma unroll
  for (int m = 0; m < 2; m++)
    #pragma unroll
    for (int e = 0; e < 16; e++) acc[m][e] = 0.f;
  float ls = 0.f;

  const int srow = t >> 3, sseg = t & 7;
  const unsigned short* kt0 = &Kg[(((b << 12) + (part << 10) + srow) << 6) + sseg * 8];
  const unsigned short* vt0 = &Vg[((b * 64 + srow) << 12) + (part << 10) + sseg * 8];
  uint4 pk0 = *(const uint4*)(kt0);
  uint4 pk1 = *(const uint4*)(kt0 + (32 << 6));
  uint4 pv0 = *(const uint4*)(vt0);
  uint4 pv1 = *(const uint4*)(vt0 + (32 << 12));

  for (int it = 0; it < 16; it++) {
    unsigned short* Kb = Kl[it & 1];
    unsigned short* Vb = Vl[it & 1];
    *(uint4*)&Kb[srow * 72 + sseg * 8] = pk0;
    *(uint4*)&Kb[(srow + 32) * 72 + sseg * 8] = pk1;
    *(uint4*)&Vb[srow * 72 + sseg * 8] = pv0;
    *(uint4*)&Vb[(srow + 32) * 72 + sseg * 8] = pv1;
    __syncthreads();                     // single barrier per iteration
    if (it < 15) {
      int j0 = (it + 1) << 6;
      pk0 = *(const uint4*)(kt0 + (j0 << 6));
      pk1 = *(const uint4*)(kt0 + ((j0 + 32) << 6));
      pv0 = *(const uint4*)(vt0 + j0);
      pv1 = *(const uint4*)(vt0 + (32 << 12) + j0);
    }

    // QK^T per 32-key tile + exp2 + pack
    unsigned int pu[2][8];
    #pragma unroll
    for (int kt = 0; kt < 2; kt++) {
      f32x16 st;
      #pragma unroll
      for (int e = 0; e < 16; e++) st[e] = 0.f;
      #pragma unroll
      for (int kc = 0; kc < 4; kc++) {
        s16x8 kf = *(const s16x8*)&Kb[(kt * 32 + q) * 72 + kc * 16 + hi * 8];
        st = __builtin_amdgcn_mfma_f32_32x32x16_bf16(kf, qf[kc], st, 0, 0, 0);
      }
      float lsum = 0.f;
      #pragma unroll
      for (int i2 = 0; i2 < 8; i2++) {
        float p0 = fexp2(st[2 * i2]);
        float p1 = fexp2(st[2 * i2 + 1]);
        lsum += p0 + p1;
        pu[kt][i2] = pk2bf(p0, p1);
      }
      ls += lsum;
    }

    // PV: build B-frags via lane^32 exchange; acc over 4 16-key chunks
    #pragma unroll
    for (int kt = 0; kt < 2; kt++) {
      #pragma unroll
      for (int c16 = 0; c16 < 2; c16++) {
        const int c16g = kt * 2 + c16;
        unsigned int a0 = pu[kt][c16 * 4 + 0], a1 = pu[kt][c16 * 4 + 1];
        unsigned int a2 = pu[kt][c16 * 4 + 2], a3 = pu[kt][c16 * 4 + 3];
        unsigned int k0 = hi ? a2 : a0, k1 = hi ? a3 : a1;  // keep block
        unsigned int s0 = hi ? a0 : a2, s1 = hi ? a1 : a3;  // send block
        unsigned int r0 = __shfl_xor(s0, 32);
        unsigned int r1 = __shfl_xor(s1, 32);
        union { s16x8 v; unsigned int u[4]; } pb;
        pb.u[0] = hi ? r0 : k0;
        pb.u[1] = hi ? r1 : k1;
        pb.u[2] = hi ? k0 : r0;
        pb.u[3] = hi ? k1 : r1;
        #pragma unroll
        for (int mtv = 0; mtv < 2; mtv++) {
          s16x8 vf = *(const s16x8*)&Vb[(mtv * 32 + q) * 72 + c16g * 16 + hi * 8];
          acc[mtv] = __builtin_amdgcn_mfma_f32_32x32x16_bf16(vf, pb.v, acc[mtv], 0, 0, 0);
        }
      }
    }
  }

  // epilogue
  ls += __shfl_xor(ls, 32);
  float inv = frcp(ls);
  const int qrow = qbase + q;
  unsigned short* orow = &Op[(((part * 8 + b) << 12) + qrow) << 6];
  #pragma unroll
  for (int mtv = 0; mtv < 2; mtv++) {
    #pragma unroll
    for (int i2 = 0; i2 < 8; i2++) {
      int dbase = ((2 * i2) & 3) + 8 * ((2 * i2) >> 2) + 4 * hi + mtv * 32;
      *(unsigned int*)&orow[dbase] =
          pk2bf(acc[mtv][2 * i2] * inv, acc[mtv][2 * i2 + 1] * inv);
    }
  }
  if (hi == 0) Lp[((part * 8 + b) << 12) + qrow] = ls;
}

// ---------------------------------------------------------------------------
// K3: combine partials -> Ot -> GEMM1(owb) -> GEMM2(g1wb,relu) -> GEMM3(g2wb,
// sigmoid) with fused x1 gating (wave 0). 32-pos tiles, grid 1024. [R12]
// ---------------------------------------------------------------------------
__global__ __launch_bounds__(256, 4) void k_out(
    const unsigned short* __restrict__ Op, const float* __restrict__ Lp,
    const unsigned short* __restrict__ owb, const float* __restrict__ obias,
    const unsigned short* __restrict__ g1wb, const float* __restrict__ g1b,
    const unsigned short* __restrict__ g2wb, const float* __restrict__ g2b,
    const float* __restrict__ x1, float* __restrict__ out,
    unsigned short* __restrict__ SWb) {
  __shared__ __align__(16) unsigned short Ot[32 * 72];
  __shared__ __align__(16) unsigned short gf2t[32 * 136];
  __shared__ __align__(16) unsigned short ht[32 * 40];
  const int blk = blockIdx.x;
  const int b = blk >> 7;
  const int i0 = (blk & 127) << 5;
  const int t = threadIdx.x;
  const int wv = t >> 6, lane = t & 63;
  const int r = lane & 15, qd = lane >> 4;
  f32x4 zf = {0.f, 0.f, 0.f, 0.f};

  {
    const int pos = t >> 3, seg = t & 7;
    const int i = i0 + pos;
    float lp4[4], lsum = 0.f;
    #pragma unroll
    for (int p = 0; p < 4; p++) { lp4[p] = Lp[((p * 8 + b) << 12) + i]; lsum += lp4[p]; }
    float o[8];
    #pragma unroll
    for (int k = 0; k < 8; k++) o[k] = 0.f;
    float invs = frcp(lsum);
    #pragma unroll
    for (int p = 0; p < 4; p++) {
      float w = lp4[p] * invs;
      uint4 u = *(const uint4*)&Op[((((p * 8 + b) << 12) + i) << 6) + seg * 8];
      o[0] += w * __uint_as_float(u.x << 16);
      o[1] += w * __uint_as_float(u.x & 0xFFFF0000u);
      o[2] += w * __uint_as_float(u.y << 16);
      o[3] += w * __uint_as_float(u.y & 0xFFFF0000u);
      o[4] += w * __uint_as_float(u.z << 16);
      o[5] += w * __uint_as_float(u.z & 0xFFFF0000u);
      o[6] += w * __uint_as_float(u.w << 16);
      o[7] += w * __uint_as_float(u.w & 0xFFFF0000u);
    }
    unsigned int* dst = (unsigned int*)&Ot[pos * 72 + seg * 8];
    #pragma unroll
    for (int k = 0; k < 4; k++) dst[k] = pk2bf(o[2 * k], o[2 * k + 1]);
  }
  __syncthreads();

  // GEMM1: gf2[oc=128][pos=32] = owb(128x64) * Ot^T; wave -> 32 oc
  {
    const int ocb = wv * 32;
    s16x8 af[2][2];
    #pragma unroll
    for (int mt = 0; mt < 2; mt++)
      #pragma unroll
      for (int ks = 0; ks < 2; ks++)
        af[mt][ks] = *(const s16x8*)&owb[(ocb + mt * 16 + r) * 64 + ks * 32 + qd * 8];
    float4 bias[2];
    #pragma unroll
    for (int mt = 0; mt < 2; mt++)
      bias[mt] = *(const float4*)&obias[ocb + mt * 16 + qd * 4];
    #pragma unroll
    for (int nt = 0; nt < 2; nt++) {
      s16x8 bfr[2];
      #pragma unroll
      for (int ks = 0; ks < 2; ks++)
        bfr[ks] = *(const s16x8*)&Ot[(nt * 16 + r) * 72 + ks * 32 + qd * 8];
      f32x4 acc[2] = {zf, zf};
      #pragma unroll
      for (int ks = 0; ks < 2; ks++)
        #pragma unroll
        for (int mt = 0; mt < 2; mt++)
          acc[mt] = __builtin_amdgcn_mfma_f32_16x16x32_bf16(af[mt][ks], bfr[ks], acc[mt], 0, 0, 0);
      #pragma unroll
      for (int mt = 0; mt < 2; mt++) {
        uint2 w;
        w.x = pk2bf(acc[mt].x + bias[mt].x, acc[mt].y + bias[mt].y);
        w.y = pk2bf(acc[mt].z + bias[mt].z, acc[mt].w + bias[mt].w);
        *(uint2*)&gf2t[(nt * 16 + r) * 136 + ocb + mt * 16 + qd * 4] = w;
      }
    }
  }
  __syncthreads();

  // GEMM2: h[oc2=32][pos=32] = g1wb(32x128)*gf2t^T; wave -> (mt, pos-tile)
  {
    const int mt = wv & 1, pt = wv >> 1;
    s16x8 af[4];
    #pragma unroll
    for (int ks = 0; ks < 4; ks++)
      af[ks] = *(const s16x8*)&g1wb[(mt * 16 + r) * 128 + ks * 32 + qd * 8];
    float4 bias = *(const float4*)&g1b[mt * 16 + qd * 4];
    s16x8 bfr[4];
    #pragma unroll
    for (int ks = 0; ks < 4; ks++)
      bfr[ks] = *(const s16x8*)&gf2t[(pt * 16 + r) * 136 + ks * 32 + qd * 8];
    f32x4 acc = zf;
    #pragma unroll
    for (int ks = 0; ks < 4; ks++)
      acc = __builtin_amdgcn_mfma_f32_16x16x32_bf16(af[ks], bfr[ks], acc, 0, 0, 0);
    uint2 w;
    w.x = pk2bf(fmaxf(acc.x + bias.x, 0.f), fmaxf(acc.y + bias.y, 0.f));
    w.y = pk2bf(fmaxf(acc.z + bias.z, 0.f), fmaxf(acc.w + bias.w, 0.f));
    *(uint2*)&ht[(pt * 16 + r) * 40 + mt * 16 + qd * 4] = w;
  }
  __syncthreads();

  // GEMM3 (swapped): sw[pos][oc3] = ht * g2wb^T; K=32; wave0 fuses x1 gate
  {
    const int nb = wv * 32;
    s16x8 bfg[2];
    float bias[2];
    #pragma unroll
    for (int ntl = 0; ntl < 2; ntl++) {
      bfg[ntl] = *(const s16x8*)&g2wb[(nb + ntl * 16 + r) * 32 + qd * 8];
      bias[ntl] = g2b[nb + ntl * 16 + r];
    }
    #pragma unroll
    for (int mt = 0; mt < 2; mt++) {
      s16x8 af = *(const s16x8*)&ht[(mt * 16 + r) * 40 + qd * 8];
      #pragma unroll
      for (int ntl = 0; ntl < 2; ntl++) {
        f32x4 acc = __builtin_amdgcn_mfma_f32_16x16x32_bf16(af, bfg[ntl], zf, 0, 0, 0);
        const int oc3 = nb + ntl * 16 + r;
        float s0 = frcp(1.0f + fexp2(-LOG2E * (acc.x + bias[ntl])));
        float s1 = frcp(1.0f + fexp2(-LOG2E * (acc.y + bias[ntl])));
        float s2 = frcp(1.0f + fexp2(-LOG2E * (acc.z + bias[ntl])));
        float s3 = frcp(1.0f + fexp2(-LOG2E * (acc.w + bias[ntl])));
        if (nb == 0) {
          const int off = ((b * 32 + oc3) << 12) + i0 + mt * 16 + qd * 4;
          float4 xv = *(const float4*)&x1[off];
          float4 o4;
          o4.x = xv.x * (1.f + s0); o4.y = xv.y * (1.f + s1);
          o4.z = xv.z * (1.f + s2); o4.w = xv.w * (1.f + s3);
          *(float4*)&out[off] = o4;
        } else {
          uint2 w; w.x = pk2bf(s0, s1); w.y = pk2bf(s2, s3);
          *(uint2*)&SWb[((b * 128 + oc3) << 12) + i0 + mt * 16 + qd * 4] = w;
        }
      }
    }
  }
}

// ---------------------------------------------------------------------------
// K4: gated outputs x2/x3/x4 only: x_k*(1+downsample(w_k)).
// ---------------------------------------------------------------------------
__device__ __forceinline__ float bilin64(const unsigned short* __restrict__ p,
                                         int oy, int ox, int n) {
  float yf = (float)oy * 63.0f / (float)n;
  int y0 = (int)yf; if (y0 > 63) y0 = 63;
  int y1 = y0 + 1;  if (y1 > 63) y1 = 63;
  float wy = yf - (float)y0;
  float xf = (float)ox * 63.0f / (float)n;
  int x0 = (int)xf; if (x0 > 63) x0 = 63;
  int x1 = x0 + 1;  if (x1 > 63) x1 = 63;
  float wx = xf - (float)x0;
  float v00 = bf2f(p[y0 * 64 + x0]), v01 = bf2f(p[y0 * 64 + x1]);
  float v10 = bf2f(p[y1 * 64 + x0]), v11 = bf2f(p[y1 * 64 + x1]);
  float top = v00 + wx * (v01 - v00);
  float bot = v10 + wx * (v11 - v10);
  return top + wy * (bot - top);
}

__global__ __launch_bounds__(256) void k_final(
    const float* __restrict__ x2, const float* __restrict__ x3,
    const float* __restrict__ x4,
    const unsigned short* __restrict__ SWb, float* __restrict__ out) {
  const int N1 = 1048576, N2 = 262144, N3 = 65536, N4 = 16384;
  int idx = blockIdx.x * 256 + threadIdx.x;
  if (idx < N2) {
    int b = idx >> 15, rr = idx & 32767;
    int c = rr >> 10, oy = (rr >> 5) & 31, ox = rr & 31;
    float w = bilin64(SWb + ((b * 128 + 32 + c) << 12), oy, ox, 31);
    out[N1 + idx] = x2[idx] * (1.f + w);
  } else if (idx < N2 + N3) {
    int i3 = idx - N2;
    int b = i3 >> 13, rr = i3 & 8191;
    int c = rr >> 8, oy = (rr >> 4) & 15, ox = rr & 15;
    float w = bilin64(SWb + ((b * 128 + 64 + c) << 12), oy, ox, 15);
    out[N1 + idx] = x3[i3] * (1.f + w);
  } else if (idx < N2 + N3 + N4) {
    int i4 = idx - N2 - N3;
    int b = i4 >> 11, rr = i4 & 2047;
    int c = rr >> 6, oy = (rr >> 3) & 7, ox = rr & 7;
    float w = bilin64(SWb + ((b * 128 + 96 + c) << 12), oy, ox, 7);
    out[N1 + idx] = x4[i4] * (1.f + w);
  }
}

// ---------------------------------------------------------------------------
extern "C" void kernel_launch(void* const* d_in, const int* in_sizes, int n_in,
                              void* d_out, int out_size, void* d_ws, size_t ws_size,
                              hipStream_t stream) {
  const float* x1  = (const float*)d_in[0];
  const float* x2  = (const float*)d_in[1];
  const float* x3  = (const float*)d_in[2];
  const float* x4  = (const float*)d_in[3];
  const float* qw  = (const float*)d_in[4];
  const float* qb  = (const float*)d_in[5];
  const float* kw  = (const float*)d_in[6];
  const float* kb  = (const float*)d_in[7];
  const float* vw  = (const float*)d_in[8];
  const float* vb  = (const float*)d_in[9];
  const float* ow  = (const float*)d_in[10];
  const float* ob  = (const float*)d_in[11];
  const float* g1w = (const float*)d_in[12];
  const float* g1b = (const float*)d_in[13];
  const float* g2w = (const float*)d_in[14];
  const float* g2b = (const float*)d_in[15];
  float* out = (float*)d_out;

  char* ws = (char*)d_ws;
  unsigned short* Qg  = (unsigned short*)(ws + 0);
  unsigned short* Kg  = (unsigned short*)(ws + 4194304);
  unsigned short* Vg  = (unsigned short*)(ws + 8388608);
  unsigned short* SWb = (unsigned short*)(ws + 0);          // aliases Q/K (dead)
  unsigned short* Op  = (unsigned short*)(ws + 12582912);
  float* Lp   = (float*)(ws + 29360128);
  unsigned short* WTb = (unsigned short*)(ws + 29884416);
  float* bqkv = (float*)(ws + 29933568);
  unsigned short* owb  = (unsigned short*)(ws + 29934592);
  unsigned short* g1wb = (unsigned short*)(ws + 29950976);
  unsigned short* g2wb = (unsigned short*)(ws + 29959168);

  k_prep<<<96, 256, 0, stream>>>(qw, qb, kw, kb, vw, vb, ow, g1w, g2w,
                                 WTb, bqkv, owb, g1wb, g2wb);
  k_qkv<<<1024, 256, 0, stream>>>(x1, x2, x3, x4, WTb, bqkv, Qg, Kg, Vg);
  k_attn<<<1024, 256, 0, stream>>>(Qg, Kg, Vg, Op, Lp);
  k_out<<<1024, 256, 0, stream>>>(Op, Lp, owb, ob, g1wb, g1b, g2wb, g2b,
                                  x1, out, SWb);
  k_final<<<1344, 256, 0, stream>>>(x2, x3, x4, SWb, out);
}